// Round 8
// baseline (1595.097 us; speedup 1.0000x reference)
//
#include <hip/hip_runtime.h>
#include <hip/hip_bf16.h>

typedef __bf16 bf16_t;
typedef __bf16 bf16x8 __attribute__((ext_vector_type(8)));
typedef float f32x4 __attribute__((ext_vector_type(4)));

#define F 128
#define KEXP 8
#define BM 64
#define STG 8192        // elems per B stage (16KB)

#define NB 196          // coarse buckets: col>>8 (256 nodes each)
#define CAP 12288       // per-bucket region capacity
#define CH 8192         // edges per binA block

// ---- init per-bucket cursors to region bases
__global__ void k_initcur(int* __restrict__ cursor){
  int t = blockIdx.x*256 + threadIdx.x;
  if (t < NB) cursor[t] = t*CAP;
}

// ---- pass A: coarse-bin edges into per-bucket regions
// 4 per-wave sub-histograms + per-wave cursors: 4x less LDS atomic contention.
__global__ __launch_bounds__(256) void k_binA(const int* __restrict__ row,
    const int* __restrict__ col, int* __restrict__ cursor,
    int* __restrict__ region, int E){
  __shared__ int stage[CH];
  __shared__ unsigned char stageb[CH];
  __shared__ int hist4[4][NB];
  __shared__ int lcur4[4][NB];
  int tid = threadIdx.x, wid = tid >> 6;
  int base = blockIdx.x * CH;
  int cnt = min(CH, E - base);
  for (int i = tid; i < 4*NB; i += 256) ((int*)hist4)[i] = 0;
  __syncthreads();
  for (int i = tid; i < cnt; i += 256){
    int r = row[base+i], c = col[base+i];
    stage[i] = (r << 8) | (c & 255);
    stageb[i] = (unsigned char)(c >> 8);
    atomicAdd(&hist4[wid][c >> 8], 1);
  }
  __syncthreads();
  for (int b = tid; b < NB; b += 256){
    int h0 = hist4[0][b], h1 = hist4[1][b], h2 = hist4[2][b], h3 = hist4[3][b];
    int gbase = atomicAdd(&cursor[b], h0+h1+h2+h3);
    lcur4[0][b] = gbase;
    lcur4[1][b] = gbase + h0;
    lcur4[2][b] = gbase + h0 + h1;
    lcur4[3][b] = gbase + h0 + h1 + h2;
  }
  __syncthreads();
  for (int i = tid; i < cnt; i += 256){
    int b = stageb[i];
    int pos = atomicAdd(&lcur4[wid][b], 1);
    region[pos] = stage[i];
  }
}

// ---- scan bucket counts -> global CSR bases; offs[N] = E
__global__ void k_bstart(const int* __restrict__ cursor, int* __restrict__ bstart,
                         int* __restrict__ offs, int Nn){
  __shared__ int lds[256];
  int t = threadIdx.x;
  int c = (t < NB) ? (cursor[t] - t*CAP) : 0;
  lds[t] = c; __syncthreads();
  for (int off=1; off<256; off<<=1){
    int u = (t>=off) ? lds[t-off] : 0;
    __syncthreads();
    lds[t] += u;
    __syncthreads();
  }
  if (t < NB) bstart[t] = lds[t] - c;
  if (t == NB-1){ bstart[NB] = lds[t]; offs[Nn] = lds[t]; }
}

// ---- pass B: per bucket, histogram 256 local dsts -> deg/offs, counting-sort
// per-wave sub-histograms + per-wave cursors.
__global__ __launch_bounds__(256) void k_binB(const int* __restrict__ region,
    const int* __restrict__ cursor, const int* __restrict__ bstart,
    int* __restrict__ deg, int* __restrict__ offs, int* __restrict__ bucket,
    int Nn){
  __shared__ int hist4[4][256];
  __shared__ int loff[256];
  __shared__ int lcur4[4][256];
  int b = blockIdx.x, t = threadIdx.x, wid = t >> 6;
  int cnt = cursor[b] - b*CAP;
  const int* src = region + b*CAP;
  for (int i = t; i < 4*256; i += 256) ((int*)hist4)[i] = 0;
  __syncthreads();
  for (int i = t; i < cnt; i += 256) atomicAdd(&hist4[wid][src[i] & 255], 1);
  __syncthreads();
  int h0 = hist4[0][t], h1 = hist4[1][t], h2 = hist4[2][t], h3 = hist4[3][t];
  int v = h0 + h1 + h2 + h3;
  loff[t] = v;
  __syncthreads();
  for (int off=1; off<256; off<<=1){
    int u = (t>=off) ? loff[t-off] : 0;
    __syncthreads();
    loff[t] += u;
    __syncthreads();
  }
  int excl = loff[t] - v;
  int gb = bstart[b];
  int node = b*256 + t;
  if (node < Nn){ deg[node] = v; offs[node] = gb + excl; }
  lcur4[0][t] = gb + excl;
  lcur4[1][t] = gb + excl + h0;
  lcur4[2][t] = gb + excl + h0 + h1;
  lcur4[3][t] = gb + excl + h0 + h1 + h2;
  __syncthreads();
  for (int i = t; i < cnt; i += 256){
    int p = src[i];
    int pos = atomicAdd(&lcur4[wid][p & 255], 1);
    bucket[pos] = p >> 8;
  }
}

// ---- xs[n][f] = bf16( rsqrt(deg[n]) * x[n][f] )  — vectorized x8
__global__ void k_prep_xs(const float* __restrict__ x, const int* __restrict__ deg,
                          bf16_t* __restrict__ xs, int total8){
  int i = blockIdx.x*256 + threadIdx.x;
  if (i < total8){
    int n = i >> 4;
    int d = deg[n];
    float dr = d>0 ? rsqrtf((float)d) : 0.f;
    const float4 f0 = *reinterpret_cast<const float4*>(&x[i*8]);
    const float4 f1 = *reinterpret_cast<const float4*>(&x[i*8+4]);
    bf16x8 v;
    v[0]=(bf16_t)(dr*f0.x); v[1]=(bf16_t)(dr*f0.y);
    v[2]=(bf16_t)(dr*f0.z); v[3]=(bf16_t)(dr*f0.w);
    v[4]=(bf16_t)(dr*f1.x); v[5]=(bf16_t)(dr*f1.y);
    v[6]=(bf16_t)(dr*f1.z); v[7]=(bf16_t)(dr*f1.w);
    *reinterpret_cast<bf16x8*>(&xs[i*8]) = v;
  }
}

// ---- Wt: frag-linear pre-tiled B (same as R7).
// stage st (0..31): h=st>>4, s2=(st>>3)&1, kk=st&7.
// frag = sl*8 + cgg; lane l, elem j:
//   f = h*128 + s2*64 + sl*32 + (l>>4)*8 + j
//   n = cgg*16 + (l&15)
__global__ void k_prep_w(const float* __restrict__ W, bf16_t* __restrict__ Wt){
  int i8 = blockIdx.x*256 + threadIdx.x;   // 32768 groups of 8 elems
  if (i8 >= 32768) return;
  int st = i8 >> 10;
  int g  = i8 & 1023;
  int frag = g >> 6;
  int lane = g & 63;
  int h = st >> 4, s2 = (st >> 3) & 1, kk = st & 7;
  int sl = frag >> 3, cgg = frag & 7;
  int n = cgg*16 + (lane & 15);
  int fbase = h*128 + s2*64 + sl*32 + (lane >> 4)*8;
  bf16x8 v;
  #pragma unroll
  for (int j=0;j<8;j++)
    v[j] = (bf16_t)W[(size_t)kk*32768 + (size_t)(fbase+j)*128 + n];
  *reinterpret_cast<bf16x8*>(&Wt[(size_t)i8*8]) = v;
}

// ---- gather-aggregate, wave-per-node, 8 gathers in flight per lane-group
__global__ __launch_bounds__(256) void k_agg(const bf16_t* __restrict__ xs,
    const int* __restrict__ offs, const int* __restrict__ bucket,
    bf16_t* __restrict__ hi, int Nn){
  int wid = threadIdx.x >> 6, lane = threadIdx.x & 63;
  int n = blockIdx.x*4 + wid;
  if (n >= Nn) return;
  int g = lane >> 4, j16 = lane & 15;
  int o0 = offs[n], o1 = offs[n+1];
  float acc[8] = {0.f,0.f,0.f,0.f,0.f,0.f,0.f,0.f};
  int j = o0 + g;
  for (; j + 28 < o1; j += 32){
    int r[8];
    #pragma unroll
    for (int t=0;t<8;t++) r[t] = bucket[j + 4*t];
    bf16x8 v[8];
    #pragma unroll
    for (int t=0;t<8;t++)
      v[t] = *reinterpret_cast<const bf16x8*>(&xs[(size_t)r[t]*F + j16*8]);
    #pragma unroll
    for (int t=0;t<8;t++)
      #pragma unroll
      for (int i=0;i<8;i++) acc[i] += (float)v[t][i];
  }
  for (; j < o1; j += 4){
    int r0 = bucket[j];
    bf16x8 v0 = *reinterpret_cast<const bf16x8*>(&xs[(size_t)r0*F + j16*8]);
    #pragma unroll
    for (int i=0;i<8;i++) acc[i] += (float)v0[i];
  }
  #pragma unroll
  for (int i=0;i<8;i++){
    acc[i] += __shfl_down(acc[i], 32);
    acc[i] += __shfl_down(acc[i], 16);
  }
  if (g == 0){
    int dn = o1 - o0;
    float dc = dn>0 ? rsqrtf((float)dn) : 0.f;
    bf16x8 o;
    #pragma unroll
    for (int i=0;i<8;i++) o[i] = (bf16_t)(dc*acc[i]);
    *reinterpret_cast<bf16x8*>(&hi[(size_t)n*F + j16*8]) = o;
  }
}

#define MFMA_BF16 __builtin_amdgcn_mfma_f32_16x16x32_bf16

// ---- fused gated expert GEMM, 64-rows-per-wave, VALU-stripped:
// BM=64; 4 col-waves x (64 rows x 32 cols each; 4 rg x 2 cg).
// Full 32-stage unroll: ping-pong B regs with static index, ck zero-init via
// MFMA C-operand (shared zero vec), compile-time A-reload points, setprio
// around MFMA cluster. Fold per stage is 32 FMA + 4 broadcast ds_reads.
// B streamed global->VGPR (frag-linear Wt, L2-resident). No loop barriers.
__global__ __launch_bounds__(256, 3) void k_gemm(
    const bf16_t* __restrict__ hi, const float* __restrict__ x,
    const float* __restrict__ e, const bf16_t* __restrict__ Wt,
    float* __restrict__ out, int Nn)
{
  __shared__ float e_sT[KEXP*BM];    // [kk][row], 2KB
  int tid = threadIdx.x;
  int base = blockIdx.x * BM;
  int lane = tid & 63, wid = tid >> 6;   // wid = col-wave (32 cols)
  int r16 = lane & 15, kc = lane >> 4;

  for (int i = tid; i < KEXP*BM; i += 256){
    int kk = i & 7, row = i >> 3;
    int srow = min(base + row, Nn-1);
    e_sT[kk*BM + row] = e[(size_t)srow*KEXP + kk];
  }

  int rr[4];
  #pragma unroll
  for (int rg=0; rg<4; rg++) rr[rg] = min(base + rg*16 + r16, Nn-1);

  // A window (hi cols 0..63)
  bf16x8 a[4][2];
  #pragma unroll
  for (int rg=0; rg<4; rg++)
    #pragma unroll
    for (int sl=0; sl<2; sl++)
      a[rg][sl] = *reinterpret_cast<const bf16x8*>(
          &hi[(size_t)rr[rg]*F + sl*32 + kc*8]);

  // B frag base: stage st, (sl,cg) at wb[st*STG + (sl*8+cg)*512]
  const bf16_t* wb = Wt + (size_t)(wid*2)*512 + (size_t)lane*8;
  bf16x8 b[2][2][2];   // [buf][sl][cg], static-indexed (full unroll)
  #pragma unroll
  for (int sl=0; sl<2; sl++)
    #pragma unroll
    for (int cg=0; cg<2; cg++)
      b[0][sl][cg] = *reinterpret_cast<const bf16x8*>(&wb[(size_t)(sl*8+cg)*512]);

  __syncthreads();   // e_sT ready (only barrier)

  f32x4 acc[4][2];
  #pragma unroll
  for (int rg=0;rg<4;rg++)
    #pragma unroll
    for (int cg=0;cg<2;cg++) acc[rg][cg] = (f32x4){0.f,0.f,0.f,0.f};
  const f32x4 fz = (f32x4){0.f,0.f,0.f,0.f};

  #pragma unroll
  for (int st=0; st<32; st++){
    // A window reloads (compile-time branch points under full unroll)
    if (st == 8){
      #pragma unroll
      for (int rg=0; rg<4; rg++)
        #pragma unroll
        for (int sl=0; sl<2; sl++)
          a[rg][sl] = *reinterpret_cast<const bf16x8*>(
              &hi[(size_t)rr[rg]*F + 64 + sl*32 + kc*8]);
    } else if (st == 16 || st == 24){
      const int off = (st == 16) ? 0 : 64;
      #pragma unroll
      for (int rg=0; rg<4; rg++)
        #pragma unroll
        for (int sl=0; sl<2; sl++){
          const float4 f0 = *reinterpret_cast<const float4*>(
              &x[(size_t)rr[rg]*F + off + sl*32 + kc*8]);
          const float4 f1 = *reinterpret_cast<const float4*>(
              &x[(size_t)rr[rg]*F + off + sl*32 + kc*8 + 4]);
          bf16x8 v;
          v[0]=(bf16_t)f0.x; v[1]=(bf16_t)f0.y; v[2]=(bf16_t)f0.z; v[3]=(bf16_t)f0.w;
          v[4]=(bf16_t)f1.x; v[5]=(bf16_t)f1.y; v[6]=(bf16_t)f1.z; v[7]=(bf16_t)f1.w;
          a[rg][sl] = v;
        }
    }

    const int cur = st & 1, nxt = cur ^ 1;
    // prefetch next stage's 4 B frags (issue before MFMAs)
    if (st < 31){
      const bf16_t* wn = wb + (size_t)(st+1)*STG;
      #pragma unroll
      for (int sl=0; sl<2; sl++)
        #pragma unroll
        for (int cg=0; cg<2; cg++)
          b[nxt][sl][cg] = *reinterpret_cast<const bf16x8*>(
              &wn[(size_t)(sl*8+cg)*512]);
    }

    // 16 MFMA: chains of 2 (sl), zero-C on first
    f32x4 ck[4][2];
    __builtin_amdgcn_s_setprio(1);
    #pragma unroll
    for (int cg=0; cg<2; cg++)
      #pragma unroll
      for (int rg=0; rg<4; rg++)
        ck[rg][cg] = MFMA_BF16(a[rg][0], b[cur][0][cg], fz, 0, 0, 0);
    #pragma unroll
    for (int cg=0; cg<2; cg++)
      #pragma unroll
      for (int rg=0; rg<4; rg++)
        ck[rg][cg] = MFMA_BF16(a[rg][1], b[cur][1][cg], ck[rg][cg], 0, 0, 0);
    __builtin_amdgcn_s_setprio(0);

    // fold expert gate (partial K fold — linear, valid)
    const int kk = st & 7;
    #pragma unroll
    for (int rg=0; rg<4; rg++){
      f32x4 ev = *reinterpret_cast<const f32x4*>(
          &e_sT[kk*BM + rg*16 + kc*4]);   // broadcast ds_read_b128
      #pragma unroll
      for (int cg=0; cg<2; cg++)
        #pragma unroll
        for (int r=0; r<4; r++)
          acc[rg][cg][r] += ev[r]*ck[rg][cg][r];
    }
  }

  // epilogue: + residual
  #pragma unroll
  for (int rg=0; rg<4; rg++){
    #pragma unroll
    for (int cg=0; cg<2; cg++){
      int ocol = wid*32 + cg*16 + r16;
      #pragma unroll
      for (int r=0; r<4; r++){
        int node = base + rg*16 + kc*4 + r;
        if (node < Nn)
          out[(size_t)node*F + ocol] = acc[rg][cg][r] + x[(size_t)node*F + ocol];
      }
    }
  }
}

extern "C" void kernel_launch(void* const* d_in, const int* in_sizes, int n_in,
                              void* d_out, int out_size, void* d_ws, size_t ws_size,
                              hipStream_t stream){
  const float* x  = (const float*)d_in[0];
  const int*  adj = (const int*)d_in[1];
  const float* e  = (const float*)d_in[2];
  const float* W  = (const float*)d_in[3];
  float* out = (float*)d_out;
  int Nn = in_sizes[0] / F;     // 50000
  int E  = in_sizes[1] / 2;     // 1600000
  const int* rowp = adj;
  const int* colp = adj + E;

  char* w = (char*)d_ws;
  auto alloc = [&](size_t b){ char* p = w; w += (b + 255) & ~(size_t)255; return p; };
  int* deg     = (int*)alloc((size_t)Nn*4);
  int* offs    = (int*)alloc(((size_t)Nn+1)*4);
  int* cursor  = (int*)alloc((size_t)NB*4);
  int* bstart  = (int*)alloc((size_t)(NB+1)*4);
  int* bucket  = (int*)alloc((size_t)E*4);
  char* uni    = alloc((size_t)Nn*F*2 > (size_t)NB*CAP*4 ? (size_t)Nn*F*2
                                                          : (size_t)NB*CAP*4);
  int* region  = (int*)uni;      // dead after k_binB
  bf16_t* xs   = (bf16_t*)uni;   // live from k_prep_xs
  bf16_t* hi   = (bf16_t*)alloc((size_t)Nn*F*2);
  bf16_t* Wt   = (bf16_t*)alloc((size_t)2048*F*2);

  int nchunks = (E + CH - 1) / CH;
  k_initcur<<<1, 256, 0, stream>>>(cursor);
  k_binA<<<nchunks, 256, 0, stream>>>(rowp, colp, cursor, region, E);
  k_bstart<<<1, 256, 0, stream>>>(cursor, bstart, offs, Nn);
  k_binB<<<NB, 256, 0, stream>>>(region, cursor, bstart, deg, offs, bucket, Nn);
  k_prep_xs<<<(Nn*F/8+255)/256, 256, 0, stream>>>(x, deg, xs, Nn*F/8);
  k_prep_w<<<(32768+255)/256, 256, 0, stream>>>(W, Wt);
  k_agg<<<(Nn+3)/4, 256, 0, stream>>>(xs, offs, bucket, hi, Nn);
  k_gemm<<<(Nn+BM-1)/BM, 256, 0, stream>>>(hi, x, e, Wt, out, Nn);
}

// Round 9
// 240.153 us; speedup vs baseline: 6.6420x; 6.6420x over previous
//
#include <hip/hip_runtime.h>
#include <hip/hip_bf16.h>

typedef __bf16 bf16_t;
typedef __bf16 bf16x8 __attribute__((ext_vector_type(8)));
typedef float f32x4 __attribute__((ext_vector_type(4)));

#define F 128
#define KEXP 8
#define BM 64
#define STG 8192        // elems per B stage (16KB)

#define NB 196          // coarse buckets: col>>8 (256 nodes each)
#define CAP 12288       // per-bucket region capacity
#define CH 8192         // edges per binA block

// ---- init per-bucket cursors to region bases
__global__ void k_initcur(int* __restrict__ cursor){
  int t = blockIdx.x*256 + threadIdx.x;
  if (t < NB) cursor[t] = t*CAP;
}

// ---- pass A: coarse-bin edges into per-bucket regions
__global__ __launch_bounds__(256) void k_binA(const int* __restrict__ row,
    const int* __restrict__ col, int* __restrict__ cursor,
    int* __restrict__ region, int E){
  __shared__ int stage[CH];
  __shared__ unsigned char stageb[CH];
  __shared__ int hist4[4][NB];
  __shared__ int lcur4[4][NB];
  int tid = threadIdx.x, wid = tid >> 6;
  int base = blockIdx.x * CH;
  int cnt = min(CH, E - base);
  for (int i = tid; i < 4*NB; i += 256) ((int*)hist4)[i] = 0;
  __syncthreads();
  for (int i = tid; i < cnt; i += 256){
    int r = row[base+i], c = col[base+i];
    stage[i] = (r << 8) | (c & 255);
    stageb[i] = (unsigned char)(c >> 8);
    atomicAdd(&hist4[wid][c >> 8], 1);
  }
  __syncthreads();
  for (int b = tid; b < NB; b += 256){
    int h0 = hist4[0][b], h1 = hist4[1][b], h2 = hist4[2][b], h3 = hist4[3][b];
    int gbase = atomicAdd(&cursor[b], h0+h1+h2+h3);
    lcur4[0][b] = gbase;
    lcur4[1][b] = gbase + h0;
    lcur4[2][b] = gbase + h0 + h1;
    lcur4[3][b] = gbase + h0 + h1 + h2;
  }
  __syncthreads();
  for (int i = tid; i < cnt; i += 256){
    int b = stageb[i];
    int pos = atomicAdd(&lcur4[wid][b], 1);
    region[pos] = stage[i];
  }
}

// ---- scan bucket counts -> global CSR bases; offs[N] = E
__global__ void k_bstart(const int* __restrict__ cursor, int* __restrict__ bstart,
                         int* __restrict__ offs, int Nn){
  __shared__ int lds[256];
  int t = threadIdx.x;
  int c = (t < NB) ? (cursor[t] - t*CAP) : 0;
  lds[t] = c; __syncthreads();
  for (int off=1; off<256; off<<=1){
    int u = (t>=off) ? lds[t-off] : 0;
    __syncthreads();
    lds[t] += u;
    __syncthreads();
  }
  if (t < NB) bstart[t] = lds[t] - c;
  if (t == NB-1){ bstart[NB] = lds[t]; offs[Nn] = lds[t]; }
}

// ---- pass B: per bucket, histogram 256 local dsts -> deg/offs, counting-sort
__global__ __launch_bounds__(256) void k_binB(const int* __restrict__ region,
    const int* __restrict__ cursor, const int* __restrict__ bstart,
    int* __restrict__ deg, int* __restrict__ offs, int* __restrict__ bucket,
    int Nn){
  __shared__ int hist4[4][256];
  __shared__ int loff[256];
  __shared__ int lcur4[4][256];
  int b = blockIdx.x, t = threadIdx.x, wid = t >> 6;
  int cnt = cursor[b] - b*CAP;
  const int* src = region + b*CAP;
  for (int i = t; i < 4*256; i += 256) ((int*)hist4)[i] = 0;
  __syncthreads();
  for (int i = t; i < cnt; i += 256) atomicAdd(&hist4[wid][src[i] & 255], 1);
  __syncthreads();
  int h0 = hist4[0][t], h1 = hist4[1][t], h2 = hist4[2][t], h3 = hist4[3][t];
  int v = h0 + h1 + h2 + h3;
  loff[t] = v;
  __syncthreads();
  for (int off=1; off<256; off<<=1){
    int u = (t>=off) ? loff[t-off] : 0;
    __syncthreads();
    loff[t] += u;
    __syncthreads();
  }
  int excl = loff[t] - v;
  int gb = bstart[b];
  int node = b*256 + t;
  if (node < Nn){ deg[node] = v; offs[node] = gb + excl; }
  lcur4[0][t] = gb + excl;
  lcur4[1][t] = gb + excl + h0;
  lcur4[2][t] = gb + excl + h0 + h1;
  lcur4[3][t] = gb + excl + h0 + h1 + h2;
  __syncthreads();
  for (int i = t; i < cnt; i += 256){
    int p = src[i];
    int pos = atomicAdd(&lcur4[wid][p & 255], 1);
    bucket[pos] = p >> 8;
  }
}

// ---- xs[n][f] = bf16( rsqrt(deg[n]) * x[n][f] )  — vectorized x8
__global__ void k_prep_xs(const float* __restrict__ x, const int* __restrict__ deg,
                          bf16_t* __restrict__ xs, int total8){
  int i = blockIdx.x*256 + threadIdx.x;
  if (i < total8){
    int n = i >> 4;
    int d = deg[n];
    float dr = d>0 ? rsqrtf((float)d) : 0.f;
    const float4 f0 = *reinterpret_cast<const float4*>(&x[i*8]);
    const float4 f1 = *reinterpret_cast<const float4*>(&x[i*8+4]);
    bf16x8 v;
    v[0]=(bf16_t)(dr*f0.x); v[1]=(bf16_t)(dr*f0.y);
    v[2]=(bf16_t)(dr*f0.z); v[3]=(bf16_t)(dr*f0.w);
    v[4]=(bf16_t)(dr*f1.x); v[5]=(bf16_t)(dr*f1.y);
    v[6]=(bf16_t)(dr*f1.z); v[7]=(bf16_t)(dr*f1.w);
    *reinterpret_cast<bf16x8*>(&xs[i*8]) = v;
  }
}

// ---- Wt: frag-linear pre-tiled B (R7 layout).
// stage st (0..31): h=st>>4, s2=(st>>3)&1, kk=st&7.
// frag = sl*8 + cgg; lane l, elem j:
//   f = h*128 + s2*64 + sl*32 + (l>>4)*8 + j
//   n = cgg*16 + (l&15)
__global__ void k_prep_w(const float* __restrict__ W, bf16_t* __restrict__ Wt){
  int i8 = blockIdx.x*256 + threadIdx.x;   // 32768 groups of 8 elems
  if (i8 >= 32768) return;
  int st = i8 >> 10;
  int g  = i8 & 1023;
  int frag = g >> 6;
  int lane = g & 63;
  int h = st >> 4, s2 = (st >> 3) & 1, kk = st & 7;
  int sl = frag >> 3, cgg = frag & 7;
  int n = cgg*16 + (lane & 15);
  int fbase = h*128 + s2*64 + sl*32 + (lane >> 4)*8;
  bf16x8 v;
  #pragma unroll
  for (int j=0;j<8;j++)
    v[j] = (bf16_t)W[(size_t)kk*32768 + (size_t)(fbase+j)*128 + n];
  *reinterpret_cast<bf16x8*>(&Wt[(size_t)i8*8]) = v;
}

// ---- gather-aggregate, wave-per-node, 8 gathers in flight per lane-group
__global__ __launch_bounds__(256) void k_agg(const bf16_t* __restrict__ xs,
    const int* __restrict__ offs, const int* __restrict__ bucket,
    bf16_t* __restrict__ hi, int Nn){
  int wid = threadIdx.x >> 6, lane = threadIdx.x & 63;
  int n = blockIdx.x*4 + wid;
  if (n >= Nn) return;
  int g = lane >> 4, j16 = lane & 15;
  int o0 = offs[n], o1 = offs[n+1];
  float acc[8] = {0.f,0.f,0.f,0.f,0.f,0.f,0.f,0.f};
  int j = o0 + g;
  for (; j + 28 < o1; j += 32){
    int r[8];
    #pragma unroll
    for (int t=0;t<8;t++) r[t] = bucket[j + 4*t];
    bf16x8 v[8];
    #pragma unroll
    for (int t=0;t<8;t++)
      v[t] = *reinterpret_cast<const bf16x8*>(&xs[(size_t)r[t]*F + j16*8]);
    #pragma unroll
    for (int t=0;t<8;t++)
      #pragma unroll
      for (int i=0;i<8;i++) acc[i] += (float)v[t][i];
  }
  for (; j < o1; j += 4){
    int r0 = bucket[j];
    bf16x8 v0 = *reinterpret_cast<const bf16x8*>(&xs[(size_t)r0*F + j16*8]);
    #pragma unroll
    for (int i=0;i<8;i++) acc[i] += (float)v0[i];
  }
  #pragma unroll
  for (int i=0;i<8;i++){
    acc[i] += __shfl_down(acc[i], 32);
    acc[i] += __shfl_down(acc[i], 16);
  }
  if (g == 0){
    int dn = o1 - o0;
    float dc = dn>0 ? rsqrtf((float)dn) : 0.f;
    bf16x8 o;
    #pragma unroll
    for (int i=0;i<8;i++) o[i] = (bf16_t)(dc*acc[i]);
    *reinterpret_cast<bf16x8*>(&hi[(size_t)n*F + j16*8]) = o;
  }
}

#define MFMA_BF16 __builtin_amdgcn_mfma_f32_16x16x32_bf16

// ---- fused gated expert GEMM, traffic-minimal + depth-2 prefetch:
// BM=64; 4 col-waves; each wave: 64 rows x 32 cols (4 rg x 2 cg).
// Outer g-loop DYNAMIC (8 iters), inner i-loop (4 stages) fully unrolled:
// all Q-buffer indices compile-time (rule-#20-safe; no scratch).
// Q[4] ring, depth-2: stage st uses Q[st&3], load st+2 -> Q[(st+2)&3].
// ck zero-init via MFMA C=fz (no movs). Fold per stage = 32 FMA only.
__global__ __launch_bounds__(256, 2) void k_gemm(
    const bf16_t* __restrict__ hi, const float* __restrict__ x,
    const float* __restrict__ e, const bf16_t* __restrict__ Wt,
    float* __restrict__ out, int Nn)
{
  __shared__ float e_sT[KEXP*BM];    // [kk][row], 2KB
  int tid = threadIdx.x;
  int base = blockIdx.x * BM;
  int lane = tid & 63, wid = tid >> 6;   // wid = col-wave (32 cols)
  int r16 = lane & 15, kc = lane >> 4;

  for (int i = tid; i < KEXP*BM; i += 256){
    int kk = i & 7, row = i >> 3;
    int srow = min(base + row, Nn-1);
    e_sT[kk*BM + row] = e[(size_t)srow*KEXP + kk];
  }

  int rr[4];
  #pragma unroll
  for (int rg=0; rg<4; rg++) rr[rg] = min(base + rg*16 + r16, Nn-1);

  // A window (h=0,s2=0): hi cols 0..63
  bf16x8 a[4][2];
  #pragma unroll
  for (int rg=0; rg<4; rg++)
    #pragma unroll
    for (int sl=0; sl<2; sl++)
      a[rg][sl] = *reinterpret_cast<const bf16x8*>(
          &hi[(size_t)rr[rg]*F + sl*32 + kc*8]);

  // B frag ring: stage st, frag (sl,cg) at wb[st*STG + (sl*8+cg)*512]
  const bf16_t* wb = Wt + (size_t)(wid*2)*512 + (size_t)lane*8;
  bf16x8 Q[4][2][2];   // ring buffer; ALL indices static
  #pragma unroll
  for (int sl=0; sl<2; sl++)
    #pragma unroll
    for (int cg=0; cg<2; cg++){
      Q[0][sl][cg] = *reinterpret_cast<const bf16x8*>(
          &wb[(size_t)(sl*8+cg)*512]);
      Q[1][sl][cg] = *reinterpret_cast<const bf16x8*>(
          &wb[(size_t)STG + (sl*8+cg)*512]);
    }

  __syncthreads();   // e_sT ready (only barrier)

  f32x4 acc[4][2];
  #pragma unroll
  for (int rg=0;rg<4;rg++)
    #pragma unroll
    for (int cg=0;cg<2;cg++) acc[rg][cg] = (f32x4){0.f,0.f,0.f,0.f};
  const f32x4 fz = (f32x4){0.f,0.f,0.f,0.f};

  for (int g=0; g<8; g++){
    // A-window reloads (uniform branches; window stable across each g-pair)
    if (g == 2){
      #pragma unroll
      for (int rg=0; rg<4; rg++)
        #pragma unroll
        for (int sl=0; sl<2; sl++)
          a[rg][sl] = *reinterpret_cast<const bf16x8*>(
              &hi[(size_t)rr[rg]*F + 64 + sl*32 + kc*8]);
    } else if (g == 4 || g == 6){
      const int off = (g == 4) ? 0 : 64;
      #pragma unroll
      for (int rg=0; rg<4; rg++)
        #pragma unroll
        for (int sl=0; sl<2; sl++){
          const float4 f0 = *reinterpret_cast<const float4*>(
              &x[(size_t)rr[rg]*F + off + sl*32 + kc*8]);
          const float4 f1 = *reinterpret_cast<const float4*>(
              &x[(size_t)rr[rg]*F + off + sl*32 + kc*8 + 4]);
          bf16x8 v;
          v[0]=(bf16_t)f0.x; v[1]=(bf16_t)f0.y; v[2]=(bf16_t)f0.z; v[3]=(bf16_t)f0.w;
          v[4]=(bf16_t)f1.x; v[5]=(bf16_t)f1.y; v[6]=(bf16_t)f1.z; v[7]=(bf16_t)f1.w;
          a[rg][sl] = v;
        }
    }

    #pragma unroll
    for (int i=0; i<4; i++){
      const int st = g*4 + i;           // g dynamic, i static
      // depth-2 prefetch: stage st+2 -> Q[(i+2)&3]  (static dst index)
      if (g < 7 || i < 2){
        const bf16_t* wn = wb + (size_t)(st+2)*STG;
        #pragma unroll
        for (int sl=0; sl<2; sl++)
          #pragma unroll
          for (int cg=0; cg<2; cg++)
            Q[(i+2)&3][sl][cg] = *reinterpret_cast<const bf16x8*>(
                &wn[(size_t)(sl*8+cg)*512]);
      }

      // 16 MFMA on Q[i] (static); ck zero via C=fz
      f32x4 ck[4][2];
      __builtin_amdgcn_s_setprio(1);
      #pragma unroll
      for (int cg=0; cg<2; cg++)
        #pragma unroll
        for (int rg=0; rg<4; rg++)
          ck[rg][cg] = MFMA_BF16(a[rg][0], Q[i][0][cg], fz, 0, 0, 0);
      #pragma unroll
      for (int cg=0; cg<2; cg++)
        #pragma unroll
        for (int rg=0; rg<4; rg++)
          ck[rg][cg] = MFMA_BF16(a[rg][1], Q[i][1][cg], ck[rg][cg], 0, 0, 0);
      __builtin_amdgcn_s_setprio(0);

      // fold expert gate kk = st&7 (partial K fold — linear, valid)
      const int kk = st & 7;
      #pragma unroll
      for (int rg=0; rg<4; rg++){
        f32x4 ev = *reinterpret_cast<const f32x4*>(
            &e_sT[kk*BM + rg*16 + kc*4]);   // broadcast ds_read_b128
        #pragma unroll
        for (int cg=0; cg<2; cg++)
          #pragma unroll
          for (int r=0; r<4; r++)
            acc[rg][cg][r] += ev[r]*ck[rg][cg][r];
      }
    }
  }

  // epilogue: + residual
  #pragma unroll
  for (int rg=0; rg<4; rg++){
    #pragma unroll
    for (int cg=0; cg<2; cg++){
      int ocol = wid*32 + cg*16 + r16;
      #pragma unroll
      for (int r=0; r<4; r++){
        int node = base + rg*16 + kc*4 + r;
        if (node < Nn)
          out[(size_t)node*F + ocol] = acc[rg][cg][r] + x[(size_t)node*F + ocol];
      }
    }
  }
}

extern "C" void kernel_launch(void* const* d_in, const int* in_sizes, int n_in,
                              void* d_out, int out_size, void* d_ws, size_t ws_size,
                              hipStream_t stream){
  const float* x  = (const float*)d_in[0];
  const int*  adj = (const int*)d_in[1];
  const float* e  = (const float*)d_in[2];
  const float* W  = (const float*)d_in[3];
  float* out = (float*)d_out;
  int Nn = in_sizes[0] / F;     // 50000
  int E  = in_sizes[1] / 2;     // 1600000
  const int* rowp = adj;
  const int* colp = adj + E;

  char* w = (char*)d_ws;
  auto alloc = [&](size_t b){ char* p = w; w += (b + 255) & ~(size_t)255; return p; };
  int* deg     = (int*)alloc((size_t)Nn*4);
  int* offs    = (int*)alloc(((size_t)Nn+1)*4);
  int* cursor  = (int*)alloc((size_t)NB*4);
  int* bstart  = (int*)alloc((size_t)(NB+1)*4);
  int* bucket  = (int*)alloc((size_t)E*4);
  char* uni    = alloc((size_t)Nn*F*2 > (size_t)NB*CAP*4 ? (size_t)Nn*F*2
                                                          : (size_t)NB*CAP*4);
  int* region  = (int*)uni;      // dead after k_binB
  bf16_t* xs   = (bf16_t*)uni;   // live from k_prep_xs
  bf16_t* hi   = (bf16_t*)alloc((size_t)Nn*F*2);
  bf16_t* Wt   = (bf16_t*)alloc((size_t)2048*F*2);

  int nchunks = (E + CH - 1) / CH;
  k_initcur<<<1, 256, 0, stream>>>(cursor);
  k_binA<<<nchunks, 256, 0, stream>>>(rowp, colp, cursor, region, E);
  k_bstart<<<1, 256, 0, stream>>>(cursor, bstart, offs, Nn);
  k_binB<<<NB, 256, 0, stream>>>(region, cursor, bstart, deg, offs, bucket, Nn);
  k_prep_xs<<<(Nn*F/8+255)/256, 256, 0, stream>>>(x, deg, xs, Nn*F/8);
  k_prep_w<<<(32768+255)/256, 256, 0, stream>>>(W, Wt);
  k_agg<<<(Nn+3)/4, 256, 0, stream>>>(xs, offs, bucket, hi, Nn);
  k_gemm<<<(Nn+BM-1)/BM, 256, 0, stream>>>(hi, x, e, Wt, out, Nn);
}

// Round 10
// 170.850 us; speedup vs baseline: 9.3362x; 1.4056x over previous
//
#include <hip/hip_runtime.h>
#include <hip/hip_bf16.h>

typedef __bf16 bf16_t;
typedef __bf16 bf16x8 __attribute__((ext_vector_type(8)));
typedef float f32x4 __attribute__((ext_vector_type(4)));

#define F 128
#define KEXP 8
#define BM 256          // rows per block (8 waves x 32 rows)
#define BSTG 32768      // elems per expert B stage (64KB)

#define NB 196          // coarse buckets: col>>8 (256 nodes each)
#define CAP 12288       // per-bucket region capacity
#define CH 8192         // edges per binA block

// ---- init per-bucket cursors to region bases
__global__ void k_initcur(int* __restrict__ cursor){
  int t = blockIdx.x*256 + threadIdx.x;
  if (t < NB) cursor[t] = t*CAP;
}

// ---- pass A: coarse-bin edges into per-bucket regions
__global__ __launch_bounds__(256) void k_binA(const int* __restrict__ row,
    const int* __restrict__ col, int* __restrict__ cursor,
    int* __restrict__ region, int E){
  __shared__ int stage[CH];
  __shared__ unsigned char stageb[CH];
  __shared__ int hist4[4][NB];
  __shared__ int lcur4[4][NB];
  int tid = threadIdx.x, wid = tid >> 6;
  int base = blockIdx.x * CH;
  int cnt = min(CH, E - base);
  for (int i = tid; i < 4*NB; i += 256) ((int*)hist4)[i] = 0;
  __syncthreads();
  for (int i = tid; i < cnt; i += 256){
    int r = row[base+i], c = col[base+i];
    stage[i] = (r << 8) | (c & 255);
    stageb[i] = (unsigned char)(c >> 8);
    atomicAdd(&hist4[wid][c >> 8], 1);
  }
  __syncthreads();
  for (int b = tid; b < NB; b += 256){
    int h0 = hist4[0][b], h1 = hist4[1][b], h2 = hist4[2][b], h3 = hist4[3][b];
    int gbase = atomicAdd(&cursor[b], h0+h1+h2+h3);
    lcur4[0][b] = gbase;
    lcur4[1][b] = gbase + h0;
    lcur4[2][b] = gbase + h0 + h1;
    lcur4[3][b] = gbase + h0 + h1 + h2;
  }
  __syncthreads();
  for (int i = tid; i < cnt; i += 256){
    int b = stageb[i];
    int pos = atomicAdd(&lcur4[wid][b], 1);
    region[pos] = stage[i];
  }
}

// ---- scan bucket counts -> global CSR bases; offs[N] = E
__global__ void k_bstart(const int* __restrict__ cursor, int* __restrict__ bstart,
                         int* __restrict__ offs, int Nn){
  __shared__ int lds[256];
  int t = threadIdx.x;
  int c = (t < NB) ? (cursor[t] - t*CAP) : 0;
  lds[t] = c; __syncthreads();
  for (int off=1; off<256; off<<=1){
    int u = (t>=off) ? lds[t-off] : 0;
    __syncthreads();
    lds[t] += u;
    __syncthreads();
  }
  if (t < NB) bstart[t] = lds[t] - c;
  if (t == NB-1){ bstart[NB] = lds[t]; offs[Nn] = lds[t]; }
}

// ---- pass B: per bucket, histogram 256 local dsts -> deg/offs, counting-sort
__global__ __launch_bounds__(256) void k_binB(const int* __restrict__ region,
    const int* __restrict__ cursor, const int* __restrict__ bstart,
    int* __restrict__ deg, int* __restrict__ offs, int* __restrict__ bucket,
    int Nn){
  __shared__ int hist4[4][256];
  __shared__ int loff[256];
  __shared__ int lcur4[4][256];
  int b = blockIdx.x, t = threadIdx.x, wid = t >> 6;
  int cnt = cursor[b] - b*CAP;
  const int* src = region + b*CAP;
  for (int i = t; i < 4*256; i += 256) ((int*)hist4)[i] = 0;
  __syncthreads();
  for (int i = t; i < cnt; i += 256) atomicAdd(&hist4[wid][src[i] & 255], 1);
  __syncthreads();
  int h0 = hist4[0][t], h1 = hist4[1][t], h2 = hist4[2][t], h3 = hist4[3][t];
  int v = h0 + h1 + h2 + h3;
  loff[t] = v;
  __syncthreads();
  for (int off=1; off<256; off<<=1){
    int u = (t>=off) ? loff[t-off] : 0;
    __syncthreads();
    loff[t] += u;
    __syncthreads();
  }
  int excl = loff[t] - v;
  int gb = bstart[b];
  int node = b*256 + t;
  if (node < Nn){ deg[node] = v; offs[node] = gb + excl; }
  lcur4[0][t] = gb + excl;
  lcur4[1][t] = gb + excl + h0;
  lcur4[2][t] = gb + excl + h0 + h1;
  lcur4[3][t] = gb + excl + h0 + h1 + h2;
  __syncthreads();
  for (int i = t; i < cnt; i += 256){
    int p = src[i];
    int pos = atomicAdd(&lcur4[wid][p & 255], 1);
    bucket[pos] = p >> 8;
  }
}

// ---- xs[n][f] = bf16( rsqrt(deg[n]) * x[n][f] )  — vectorized x8
__global__ void k_prep_xs(const float* __restrict__ x, const int* __restrict__ deg,
                          bf16_t* __restrict__ xs, int total8){
  int i = blockIdx.x*256 + threadIdx.x;
  if (i < total8){
    int n = i >> 4;
    int d = deg[n];
    float dr = d>0 ? rsqrtf((float)d) : 0.f;
    const float4 f0 = *reinterpret_cast<const float4*>(&x[i*8]);
    const float4 f1 = *reinterpret_cast<const float4*>(&x[i*8+4]);
    bf16x8 v;
    v[0]=(bf16_t)(dr*f0.x); v[1]=(bf16_t)(dr*f0.y);
    v[2]=(bf16_t)(dr*f0.z); v[3]=(bf16_t)(dr*f0.w);
    v[4]=(bf16_t)(dr*f1.x); v[5]=(bf16_t)(dr*f1.y);
    v[6]=(bf16_t)(dr*f1.z); v[7]=(bf16_t)(dr*f1.w);
    *reinterpret_cast<bf16x8*>(&xs[i*8]) = v;
  }
}

// ---- Wt: expert-major frag-linear B.
// Wt[kk*32768 + frag*512 + lane*8 + j], frag = ks*8 + cg (ks 0..7 over K=256,
// cg 0..7 over 128 out-cols):  f = ks*32 + (lane>>4)*8 + j  (hicat K col),
// n = cg*16 + (lane&15).  src = W[kk][f][n].
__global__ void k_prep_w(const float* __restrict__ W, bf16_t* __restrict__ Wt){
  int i8 = blockIdx.x*256 + threadIdx.x;   // 32768 groups of 8 elems
  if (i8 >= 32768) return;
  int kk   = i8 >> 12;
  int frag = (i8 >> 6) & 63;
  int lane = i8 & 63;
  int ks = frag >> 3, cg = frag & 7;
  int n  = cg*16 + (lane & 15);
  int f0 = ks*32 + (lane >> 4)*8;
  bf16x8 v;
  #pragma unroll
  for (int j=0;j<8;j++)
    v[j] = (bf16_t)W[(size_t)kk*32768 + (size_t)(f0+j)*128 + n];
  *reinterpret_cast<bf16x8*>(&Wt[(size_t)i8*8]) = v;
}

// ---- gather-aggregate, wave-per-node, 8 gathers in flight per lane-group
__global__ __launch_bounds__(256) void k_agg(const bf16_t* __restrict__ xs,
    const int* __restrict__ offs, const int* __restrict__ bucket,
    bf16_t* __restrict__ hi, int Nn){
  int wid = threadIdx.x >> 6, lane = threadIdx.x & 63;
  int n = blockIdx.x*4 + wid;
  if (n >= Nn) return;
  int g = lane >> 4, j16 = lane & 15;
  int o0 = offs[n], o1 = offs[n+1];
  float acc[8] = {0.f,0.f,0.f,0.f,0.f,0.f,0.f,0.f};
  int j = o0 + g;
  for (; j + 28 < o1; j += 32){
    int r[8];
    #pragma unroll
    for (int t=0;t<8;t++) r[t] = bucket[j + 4*t];
    bf16x8 v[8];
    #pragma unroll
    for (int t=0;t<8;t++)
      v[t] = *reinterpret_cast<const bf16x8*>(&xs[(size_t)r[t]*F + j16*8]);
    #pragma unroll
    for (int t=0;t<8;t++)
      #pragma unroll
      for (int i=0;i<8;i++) acc[i] += (float)v[t][i];
  }
  for (; j < o1; j += 4){
    int r0 = bucket[j];
    bf16x8 v0 = *reinterpret_cast<const bf16x8*>(&xs[(size_t)r0*F + j16*8]);
    #pragma unroll
    for (int i=0;i<8;i++) acc[i] += (float)v0[i];
  }
  #pragma unroll
  for (int i=0;i<8;i++){
    acc[i] += __shfl_down(acc[i], 32);
    acc[i] += __shfl_down(acc[i], 16);
  }
  if (g == 0){
    int dn = o1 - o0;
    float dc = dn>0 ? rsqrtf((float)dn) : 0.f;
    bf16x8 o;
    #pragma unroll
    for (int i=0;i<8;i++) o[i] = (bf16_t)(dc*acc[i]);
    *reinterpret_cast<bf16x8*>(&hi[(size_t)n*F + j16*8]) = o;
  }
}

#define MFMA_BF16 __builtin_amdgcn_mfma_f32_16x16x32_bf16

// ---- fused gated expert GEMM, expert-staged LDS DMA:
// BM=256, 512 thr = 8 waves x 32 rows; A (full K=256) register-resident
// (64 VGPR). Loop over 8 experts: B_k (64KB) DMA'd via global_load_lds into
// 2x64KB LDS dbuf; counted vmcnt(8) + raw s_barrier (loads span barriers);
// per-expert: 64 ds_read_b128 + 128 MFMA + e-gate fold (64 FMA).
__global__ __launch_bounds__(512, 2) void k_gemm(
    const bf16_t* __restrict__ hi, const float* __restrict__ x,
    const float* __restrict__ e, const bf16_t* __restrict__ Wt,
    float* __restrict__ out, int Nn)
{
  extern __shared__ __align__(16) char smem[];     // 2*64KB B + 8KB e
  bf16_t* b_s  = (bf16_t*)smem;
  float*  e_sT = (float*)(smem + 2*BSTG*2);        // [kk][256 rows]
  const int tid = threadIdx.x;
  const int base = blockIdx.x * BM;
  const int lane = tid & 63, wid = tid >> 6;
  const int r16 = lane & 15, kc = lane >> 4;

  // issue expert-0 B DMA immediately (latency head start)
  {
    const bf16_t* src = Wt;
    bf16_t* dst = b_s;
    #pragma unroll
    for (int i=0;i<8;i++){
      int u = tid + i*512;
      __builtin_amdgcn_global_load_lds(
          (const __attribute__((address_space(1))) void*)(src + (size_t)u*8),
          (__attribute__((address_space(3))) void*)(dst + (size_t)u*8),
          16, 0, 0);
    }
  }

  // stage e gates: e_sT[kk][row]
  for (int i = tid; i < KEXP*BM; i += 512){
    int kk = i >> 8, row = i & (BM-1);
    int srow = min(base + row, Nn-1);
    e_sT[kk*BM + row] = e[(size_t)srow*KEXP + kk];
  }

  // A frags: rows wid*32 + {0,16} + r16, full K=256 (hi || bf16(x))
  int rA = min(base + wid*32 + r16,      Nn-1);
  int rB = min(base + wid*32 + 16 + r16, Nn-1);
  bf16x8 a[2][8];
  #pragma unroll
  for (int ks=0; ks<4; ks++){
    a[0][ks] = *reinterpret_cast<const bf16x8*>(&hi[(size_t)rA*F + ks*32 + kc*8]);
    a[1][ks] = *reinterpret_cast<const bf16x8*>(&hi[(size_t)rB*F + ks*32 + kc*8]);
  }
  #pragma unroll
  for (int ks=0; ks<4; ks++){
    const float4 f0 = *reinterpret_cast<const float4*>(&x[(size_t)rA*F + ks*32 + kc*8]);
    const float4 f1 = *reinterpret_cast<const float4*>(&x[(size_t)rA*F + ks*32 + kc*8 + 4]);
    bf16x8 v;
    v[0]=(bf16_t)f0.x; v[1]=(bf16_t)f0.y; v[2]=(bf16_t)f0.z; v[3]=(bf16_t)f0.w;
    v[4]=(bf16_t)f1.x; v[5]=(bf16_t)f1.y; v[6]=(bf16_t)f1.z; v[7]=(bf16_t)f1.w;
    a[0][4+ks] = v;
    const float4 g0 = *reinterpret_cast<const float4*>(&x[(size_t)rB*F + ks*32 + kc*8]);
    const float4 g1 = *reinterpret_cast<const float4*>(&x[(size_t)rB*F + ks*32 + kc*8 + 4]);
    bf16x8 u;
    u[0]=(bf16_t)g0.x; u[1]=(bf16_t)g0.y; u[2]=(bf16_t)g0.z; u[3]=(bf16_t)g0.w;
    u[4]=(bf16_t)g1.x; u[5]=(bf16_t)g1.y; u[6]=(bf16_t)g1.z; u[7]=(bf16_t)g1.w;
    a[1][4+ks] = u;
  }

  f32x4 acc[2][8];
  #pragma unroll
  for (int rg=0;rg<2;rg++)
    #pragma unroll
    for (int cg=0;cg<8;cg++) acc[rg][cg] = (f32x4){0.f,0.f,0.f,0.f};
  const f32x4 fz = (f32x4){0.f,0.f,0.f,0.f};

  // prologue sync: my DMA + everyone's e_sT writes done
  asm volatile("s_waitcnt vmcnt(0) lgkmcnt(0)" ::: "memory");
  __builtin_amdgcn_s_barrier();

  for (int kk=0; kk<8; kk++){
    // issue next expert's B DMA into the other buffer
    if (kk < 7){
      const bf16_t* src = Wt + (size_t)(kk+1)*BSTG;
      bf16_t* dst = b_s + ((kk+1)&1)*BSTG;
      #pragma unroll
      for (int i=0;i<8;i++){
        int u = tid + i*512;
        __builtin_amdgcn_global_load_lds(
            (const __attribute__((address_space(1))) void*)(src + (size_t)u*8),
            (__attribute__((address_space(3))) void*)(dst + (size_t)u*8),
            16, 0, 0);
      }
      asm volatile("s_waitcnt vmcnt(8)" ::: "memory");  // my stage-kk loads done
    } else {
      asm volatile("s_waitcnt vmcnt(0)" ::: "memory");
    }
    __builtin_amdgcn_s_barrier();   // B1: buf[kk&1] globally ready

    const bf16_t* buf = b_s + (kk&1)*BSTG;
    f32x4 ev0 = *reinterpret_cast<const f32x4*>(&e_sT[kk*BM + wid*32 + kc*4]);
    f32x4 ev1 = *reinterpret_cast<const f32x4*>(&e_sT[kk*BM + wid*32 + 16 + kc*4]);

    #pragma unroll
    for (int cgh=0; cgh<2; cgh++){
      f32x4 ck[2][4];
      __builtin_amdgcn_s_setprio(1);
      #pragma unroll
      for (int cg=0; cg<4; cg++){
        bf16x8 b = *reinterpret_cast<const bf16x8*>(
            &buf[(size_t)(cgh*4 + cg)*512 + lane*8]);
        ck[0][cg] = MFMA_BF16(a[0][0], b, fz, 0, 0, 0);
        ck[1][cg] = MFMA_BF16(a[1][0], b, fz, 0, 0, 0);
      }
      #pragma unroll
      for (int ks=1; ks<8; ks++)
        #pragma unroll
        for (int cg=0; cg<4; cg++){
          bf16x8 b = *reinterpret_cast<const bf16x8*>(
              &buf[(size_t)(ks*8 + cgh*4 + cg)*512 + lane*8]);
          ck[0][cg] = MFMA_BF16(a[0][ks], b, ck[0][cg], 0, 0, 0);
          ck[1][cg] = MFMA_BF16(a[1][ks], b, ck[1][cg], 0, 0, 0);
        }
      __builtin_amdgcn_s_setprio(0);
      #pragma unroll
      for (int cg=0; cg<4; cg++)
        #pragma unroll
        for (int r=0; r<4; r++){
          acc[0][cgh*4+cg][r] += ev0[r]*ck[0][cg][r];
          acc[1][cgh*4+cg][r] += ev1[r]*ck[1][cg][r];
        }
    }

    __builtin_amdgcn_s_barrier();   // B2: reads done before buf re-staged
  }

  // epilogue: + residual
  #pragma unroll
  for (int rg=0; rg<2; rg++){
    #pragma unroll
    for (int cg=0; cg<8; cg++){
      int ocol = cg*16 + r16;
      #pragma unroll
      for (int r=0; r<4; r++){
        int node = base + wid*32 + rg*16 + kc*4 + r;
        if (node < Nn)
          out[(size_t)node*F + ocol] = acc[rg][cg][r] + x[(size_t)node*F + ocol];
      }
    }
  }
}

extern "C" void kernel_launch(void* const* d_in, const int* in_sizes, int n_in,
                              void* d_out, int out_size, void* d_ws, size_t ws_size,
                              hipStream_t stream){
  const float* x  = (const float*)d_in[0];
  const int*  adj = (const int*)d_in[1];
  const float* e  = (const float*)d_in[2];
  const float* W  = (const float*)d_in[3];
  float* out = (float*)d_out;
  int Nn = in_sizes[0] / F;     // 50000
  int E  = in_sizes[1] / 2;     // 1600000
  const int* rowp = adj;
  const int* colp = adj + E;

  char* w = (char*)d_ws;
  auto alloc = [&](size_t b){ char* p = w; w += (b + 255) & ~(size_t)255; return p; };
  int* deg     = (int*)alloc((size_t)Nn*4);
  int* offs    = (int*)alloc(((size_t)Nn+1)*4);
  int* cursor  = (int*)alloc((size_t)NB*4);
  int* bstart  = (int*)alloc((size_t)(NB+1)*4);
  int* bucket  = (int*)alloc((size_t)E*4);
  char* uni    = alloc((size_t)Nn*F*2 > (size_t)NB*CAP*4 ? (size_t)Nn*F*2
                                                          : (size_t)NB*CAP*4);
  int* region  = (int*)uni;      // dead after k_binB
  bf16_t* xs   = (bf16_t*)uni;   // live from k_prep_xs
  bf16_t* hi   = (bf16_t*)alloc((size_t)Nn*F*2);
  bf16_t* Wt   = (bf16_t*)alloc((size_t)2048*F*2);

  const int smem_bytes = 2*BSTG*2 + KEXP*BM*4;   // 131072 + 8192 = 139264
  hipFuncSetAttribute((const void*)k_gemm,
                      hipFuncAttributeMaxDynamicSharedMemorySize, smem_bytes);

  int nchunks = (E + CH - 1) / CH;
  k_initcur<<<1, 256, 0, stream>>>(cursor);
  k_binA<<<nchunks, 256, 0, stream>>>(rowp, colp, cursor, region, E);
  k_bstart<<<1, 256, 0, stream>>>(cursor, bstart, offs, Nn);
  k_binB<<<NB, 256, 0, stream>>>(region, cursor, bstart, deg, offs, bucket, Nn);
  k_prep_xs<<<(Nn*F/8+255)/256, 256, 0, stream>>>(x, deg, xs, Nn*F/8);
  k_prep_w<<<(32768+255)/256, 256, 0, stream>>>(W, Wt);
  k_agg<<<(Nn+3)/4, 256, 0, stream>>>(xs, offs, bucket, hi, Nn);
  k_gemm<<<(Nn+BM-1)/BM, 512, smem_bytes, stream>>>(hi, x, e, Wt, out, Nn);
}